// Round 1
// baseline (334.634 us; speedup 1.0000x reference)
//
#include <hip/hip_runtime.h>
#include <math.h>
#include <float.h>
#include <limits.h>

// Problem constants
#define PIX   13824   // 64*216
#define QPIX  3456    // 32*108
#define QW    108
#define QH    32
#define NPTS  8192
#define MCAP  4096

// ---------------------------------------------------------------------------
// K1: feat/value linear maps + fold to [r][k][c] pixel-major + feat inv-norm
// block = 256 (4 waves; wave q owns output channels q*16..q*16+15), grid = 216
// ---------------------------------------------------------------------------
__global__ __launch_bounds__(256) void k1_linmaps(
    const float* __restrict__ x, const float* __restrict__ Wf, const float* __restrict__ bf,
    const float* __restrict__ Wv, const float* __restrict__ bv,
    float* __restrict__ featp, float* __restrict__ valp, float* __restrict__ invn)
{
    __shared__ float ssq[4][64];
    int t = threadIdx.x;
    int lane = t & 63;
    int q = t >> 6;                       // wave id -> o-group (wave-uniform)
    int pix = blockIdx.x * 64 + lane;     // 216*64 = 13824 exact
    int h = pix / 216;
    int w = pix - h * 216;
    int r = ((h >> 5) << 1) | (w >= QW ? 1 : 0);
    int k = (h & 31) * QW + (w >= QW ? w - QW : w);

    float xr[64];
    #pragma unroll
    for (int c = 0; c < 64; c++) xr[c] = x[c * PIX + pix];

    size_t base = ((size_t)(r * QPIX + k)) * 64 + q * 16;
    float ss = 0.0f;
    for (int i = 0; i < 16; i++) {
        int o = q * 16 + i;               // wave-uniform
        float af = bf[o], av = bv[o];
        #pragma unroll
        for (int c = 0; c < 64; c++) {
            af = fmaf(Wf[o * 64 + c], xr[c], af);
            av = fmaf(Wv[o * 64 + c], xr[c], av);
        }
        featp[base + i] = af;
        valp[base + i]  = av;
        ss += af * af;
    }
    ssq[q][lane] = ss;
    __syncthreads();
    if (q == 0) {
        float tot = ssq[0][lane] + ssq[1][lane] + ssq[2][lane] + ssq[3][lane];
        invn[r * QPIX + k] = 1.0f / fmaxf(sqrtf(tot), 1e-12f);
    }
}

// ---------------------------------------------------------------------------
// K2: order-preserving per-quadrant compaction (single wave, ballot scan)
// ---------------------------------------------------------------------------
__global__ __launch_bounds__(64) void k2_compact(
    const float* __restrict__ points,
    float* __restrict__ cp, int* __restrict__ counts, int* __restrict__ slot)
{
    int lane = threadIdx.x;
    const float2* pts = (const float2*)points;
    int cnt[4] = {0, 0, 0, 0};
    unsigned long long below = (lane == 0) ? 0ull : (~0ull >> (64 - lane));
    for (int b = 0; b < 8; b++) {
        float2 pt[16];
        #pragma unroll
        for (int i = 0; i < 16; i++) pt[i] = pts[(b * 16 + i) * 64 + lane];
        #pragma unroll
        for (int i = 0; i < 16; i++) {
            int n = (b * 16 + i) * 64 + lane;
            float px = pt[i].x, py = pt[i].y;
            // rh = 384/2 = 192 exact, rw = 1296/2 = 648 exact
            int q = ((py > 192.0f) ? 2 : 0) + ((px > 648.0f) ? 1 : 0);
            #pragma unroll
            for (int r = 0; r < 4; r++) {
                unsigned long long m = __ballot(q == r);
                if (q == r) {
                    int pos = cnt[r] + __popcll(m & below);
                    ((float2*)cp)[r * MCAP + pos] = pt[i];
                    slot[n] = r * MCAP + pos;
                }
                cnt[r] += __popcll(m);
            }
        }
    }
    if (lane == 0) {
        counts[0] = cnt[0]; counts[1] = cnt[1];
        counts[2] = cnt[2]; counts[3] = cnt[3];
    }
}

// ---------------------------------------------------------------------------
// K3: bilinear gather (border clamp, align_corners=False) of feat & value at
// compacted points; slot m == K_r is the phantom (0,0) padded row.
// Normalized centers cn, raw value centers vc, both [r][m][c] row-major.
// ---------------------------------------------------------------------------
__global__ __launch_bounds__(64) void k3_gather(
    const float* __restrict__ featp, const float* __restrict__ valp,
    const float* __restrict__ cp, const int* __restrict__ counts,
    float* __restrict__ cn, float* __restrict__ vc)
{
    int r = blockIdx.y;
    int m = blockIdx.x * 64 + threadIdx.x;
    int K = counts[r];
    int Mr = min(K + 1, MCAP);
    if (m >= Mr) return;
    float px = 0.0f, py = 0.0f;
    if (m < K) { float2 p = ((const float2*)cp)[r * MCAP + m]; px = p.x; py = p.y; }

    // mirror reference op order: grid = p/(S-1)*2-1 ; g = (grid+1)*(D/2)-0.5
    float gx = (px / 1295.0f * 2.0f - 1.0f + 1.0f) * 54.0f - 0.5f;
    float gy = (py / 383.0f  * 2.0f - 1.0f + 1.0f) * 16.0f - 0.5f;
    float x0 = floorf(gx), y0 = floorf(gy);
    float wx = gx - x0, wy = gy - y0;
    int x0i = (int)fminf(fmaxf(x0,         0.0f), 107.0f);
    int x1i = (int)fminf(fmaxf(x0 + 1.0f,  0.0f), 107.0f);
    int y0i = (int)fminf(fmaxf(y0,         0.0f), 31.0f);
    int y1i = (int)fminf(fmaxf(y0 + 1.0f,  0.0f), 31.0f);
    float w00 = (1.0f - wx) * (1.0f - wy);
    float w01 = wx * (1.0f - wy);
    float w10 = (1.0f - wx) * wy;
    float w11 = wx * wy;

    size_t b00 = ((size_t)(r * QPIX + y0i * QW + x0i)) * 64;
    size_t b01 = ((size_t)(r * QPIX + y0i * QW + x1i)) * 64;
    size_t b10 = ((size_t)(r * QPIX + y1i * QW + x0i)) * 64;
    size_t b11 = ((size_t)(r * QPIX + y1i * QW + x1i)) * 64;
    size_t ob  = ((size_t)(r * MCAP + m)) * 64;

    float fr[64];
    float ss = 0.0f;
    #pragma unroll
    for (int c = 0; c < 64; c += 4) {
        float4 a  = *(const float4*)(featp + b00 + c);
        float4 b_ = *(const float4*)(featp + b01 + c);
        float4 g  = *(const float4*)(featp + b10 + c);
        float4 d  = *(const float4*)(featp + b11 + c);
        float e0 = a.x * w00 + b_.x * w01 + g.x * w10 + d.x * w11;
        float e1 = a.y * w00 + b_.y * w01 + g.y * w10 + d.y * w11;
        float e2 = a.z * w00 + b_.z * w01 + g.z * w10 + d.z * w11;
        float e3 = a.w * w00 + b_.w * w01 + g.w * w10 + d.w * w11;
        fr[c] = e0; fr[c+1] = e1; fr[c+2] = e2; fr[c+3] = e3;
        ss += e0*e0; ss += e1*e1; ss += e2*e2; ss += e3*e3;
    }
    float inv = 1.0f / fmaxf(sqrtf(ss), 1e-12f);
    #pragma unroll
    for (int c = 0; c < 64; c += 4) {
        *(float4*)(cn + ob + c) =
            make_float4(fr[c]*inv, fr[c+1]*inv, fr[c+2]*inv, fr[c+3]*inv);
    }
    #pragma unroll
    for (int c = 0; c < 64; c += 4) {
        float4 a  = *(const float4*)(valp + b00 + c);
        float4 b_ = *(const float4*)(valp + b01 + c);
        float4 g  = *(const float4*)(valp + b10 + c);
        float4 d  = *(const float4*)(valp + b11 + c);
        float4 o;
        o.x = a.x * w00 + b_.x * w01 + g.x * w10 + d.x * w11;
        o.y = a.y * w00 + b_.y * w01 + g.y * w10 + d.y * w11;
        o.z = a.z * w00 + b_.z * w01 + g.z * w10 + d.z * w11;
        o.w = a.w * w00 + b_.w * w01 + g.w * w10 + d.w * w11;
        *(float4*)(vc + ob + c) = o;
    }
}

// ---------------------------------------------------------------------------
// K4: cosine-sim argmax assignment + weighted scatter-aggregate.
// Block = (16 tx keys) x (16 ty centers) threads, 4x4 register tile,
// 64-key tile per block, loop over all center tiles of the quadrant.
// LDS row stride 68 floats (16B aligned; worst aliasing 2-way = free).
// ---------------------------------------------------------------------------
#define AS 68
__global__ __launch_bounds__(256) void k4_sim(
    const float* __restrict__ featp, const float* __restrict__ invn,
    const float* __restrict__ cn, const float* __restrict__ valp,
    const int* __restrict__ counts,
    const float* __restrict__ alpha_p, const float* __restrict__ beta_p,
    float* __restrict__ agg, float* __restrict__ denom)
{
    __shared__ float A[64 * AS];
    __shared__ float B[64 * AS];
    __shared__ float rs[16][17];
    __shared__ int   rm[16][17];
    __shared__ float win_s[64];
    __shared__ int   win_m[64];

    int r  = blockIdx.y;
    int k0 = blockIdx.x * 64;
    int t  = threadIdx.x;
    int tx = t & 15, ty = t >> 4;
    int K  = counts[r];
    int Mr = min(K + 1, MCAP);
    float alpha = alpha_p[0], beta = beta_p[0];

    // load B tile: 64 keys x 64 ch, normalized (xn)
    {
        int j = t >> 2, cq = (t & 3) * 16;
        float inv = invn[r * QPIX + k0 + j];
        const float* src = featp + ((size_t)(r * QPIX + k0 + j)) * 64 + cq;
        float* dst = B + j * AS + cq;
        #pragma unroll
        for (int i = 0; i < 16; i += 4) {
            float4 fv = *(const float4*)(src + i);
            fv.x *= inv; fv.y *= inv; fv.z *= inv; fv.w *= inv;
            *(float4*)(dst + i) = fv;
        }
    }

    float best_s[4] = {-INFINITY, -INFINITY, -INFINITY, -INFINITY};
    int   best_m[4] = {INT_MAX, INT_MAX, INT_MAX, INT_MAX};

    int ntiles = (Mr + 63) >> 6;
    for (int ct = 0; ct < ntiles; ct++) {
        __syncthreads();   // previous tile's A reads done (also covers B load)
        {
            int row = t >> 2, cq = (t & 3) * 16;
            int mg = min(ct * 64 + row, MCAP - 1);
            const float* src = cn + ((size_t)(r * MCAP + mg)) * 64 + cq;
            float* dst = A + row * AS + cq;
            #pragma unroll
            for (int i = 0; i < 16; i += 4)
                *(float4*)(dst + i) = *(const float4*)(src + i);
        }
        __syncthreads();

        float dot[4][4] = {};
        #pragma unroll
        for (int cc = 0; cc < 64; cc += 4) {
            float4 av[4], bv[4];
            #pragma unroll
            for (int u = 0; u < 4; u++) av[u] = *(const float4*)(A + (ty + 16*u) * AS + cc);
            #pragma unroll
            for (int v = 0; v < 4; v++) bv[v] = *(const float4*)(B + (tx + 16*v) * AS + cc);
            #pragma unroll
            for (int u = 0; u < 4; u++) {
                #pragma unroll
                for (int v = 0; v < 4; v++) {
                    dot[u][v] = fmaf(av[u].x, bv[v].x, dot[u][v]);
                    dot[u][v] = fmaf(av[u].y, bv[v].y, dot[u][v]);
                    dot[u][v] = fmaf(av[u].z, bv[v].z, dot[u][v]);
                    dot[u][v] = fmaf(av[u].w, bv[v].w, dot[u][v]);
                }
            }
        }
        // running argmax; m ascending within thread (u asc), strict > keeps
        // the smallest m on exact fp32 ties (reference first-max rule)
        #pragma unroll
        for (int u = 0; u < 4; u++) {
            int mg = ct * 64 + ty + 16 * u;
            bool valid = mg < Mr;
            #pragma unroll
            for (int v = 0; v < 4; v++) {
                float s = fmaf(alpha, dot[u][v], beta);   // monotone w/ sigmoid
                if (valid && s > best_s[v]) { best_s[v] = s; best_m[v] = mg; }
            }
        }
    }

    // cross-thread (ty) reduce per key; tie -> smaller m
    #pragma unroll
    for (int v = 0; v < 4; v++) {
        __syncthreads();
        rs[ty][tx] = best_s[v]; rm[ty][tx] = best_m[v];
        __syncthreads();
        for (int st = 8; st > 0; st >>= 1) {
            if (ty < st) {
                float s2 = rs[ty + st][tx]; int m2 = rm[ty + st][tx];
                if (s2 > rs[ty][tx] || (s2 == rs[ty][tx] && m2 < rm[ty][tx])) {
                    rs[ty][tx] = s2; rm[ty][tx] = m2;
                }
            }
            __syncthreads();
        }
        if (ty == 0) { win_s[tx + 16 * v] = rs[0][tx]; win_m[tx + 16 * v] = rm[0][tx]; }
    }
    __syncthreads();

    // scatter: 4 threads per key, 16 channels each; skip phantom winners
    {
        int j = t >> 2, cq = (t & 3) * 16;
        int wm = win_m[j];
        if (wm < K) {
            float wgt = 1.0f / (1.0f + expf(-win_s[j]));
            float* ad = agg + ((size_t)(r * MCAP + wm)) * 64 + cq;
            const float* vsrc = valp + ((size_t)(r * QPIX + k0 + j)) * 64 + cq;
            #pragma unroll
            for (int i = 0; i < 16; i++) atomicAdd(ad + i, wgt * vsrc[i]);
            if ((t & 3) == 0) atomicAdd(denom + r * MCAP + wm, wgt);
        }
    }
}

// ---------------------------------------------------------------------------
// K5: per-point output + projection + transposed store [1,64,1,8192]
// block = 256 = 4 points x 64 channels (one wave per point)
// ---------------------------------------------------------------------------
__global__ __launch_bounds__(256) void k5_out(
    const float* __restrict__ agg, const float* __restrict__ vc,
    const float* __restrict__ denom, const int* __restrict__ slot,
    const float* __restrict__ Wp, const float* __restrict__ bp,
    float* __restrict__ out)
{
    __shared__ float WT[64 * 65];
    __shared__ float ov[4][64];
    __shared__ float res[4][64];
    int t = threadIdx.x;
    {
        int o = t >> 2, cq = (t & 3) * 16;
        #pragma unroll
        for (int i = 0; i < 16; i += 4) {
            float4 wv = *(const float4*)(Wp + o * 64 + cq + i);
            WT[(cq + i + 0) * 65 + o] = wv.x;
            WT[(cq + i + 1) * 65 + o] = wv.y;
            WT[(cq + i + 2) * 65 + o] = wv.z;
            WT[(cq + i + 3) * 65 + o] = wv.w;
        }
    }
    int p = t >> 6, c = t & 63;
    int n = blockIdx.x * 4 + p;
    int sl = slot[n];
    float d = denom[sl] + 1.0f;
    float o_v = (agg[(size_t)sl * 64 + c] + vc[(size_t)sl * 64 + c]) / d;
    ov[p][c] = o_v;
    unsigned long long nz = __ballot(o_v != 0.0f);   // wave == point
    __syncthreads();
    float acc = bp[c];
    #pragma unroll
    for (int cc = 0; cc < 64; cc++)
        acc = fmaf(ov[p][cc], WT[cc * 65 + c], acc);
    res[p][c] = (nz != 0ull) ? acc : 0.0f;
    __syncthreads();
    if (t < 64) {
        float4 val = make_float4(res[0][t], res[1][t], res[2][t], res[3][t]);
        *(float4*)(out + (size_t)t * NPTS + blockIdx.x * 4) = val;
    }
}

// ---------------------------------------------------------------------------
extern "C" void kernel_launch(void* const* d_in, const int* in_sizes, int n_in,
                              void* d_out, int out_size, void* d_ws, size_t ws_size,
                              hipStream_t stream) {
    const float* points = (const float*)d_in[0];
    const float* x      = (const float*)d_in[1];
    const float* Wf     = (const float*)d_in[2];
    const float* bf     = (const float*)d_in[3];
    const float* Wv     = (const float*)d_in[4];
    const float* bv     = (const float*)d_in[5];
    const float* Wp     = (const float*)d_in[6];
    const float* bp     = (const float*)d_in[7];
    const float* alpha  = (const float*)d_in[8];
    const float* beta   = (const float*)d_in[9];
    float* out = (float*)d_out;

    float* ws    = (float*)d_ws;
    float* featp = ws;                       // 884736
    float* valp  = featp + 884736;           // 884736
    float* cn    = valp  + 884736;           // 1048576
    float* vc    = cn    + 1048576;          // 1048576
    float* agg   = vc    + 1048576;          // 1048576
    float* denom = agg   + 1048576;          // 16384
    float* invn  = denom + 16384;            // 13824
    float* cp    = invn  + 13824;            // 32768
    int*   counts= (int*)(cp + 32768);       // 16
    int*   slot  = counts + 16;              // 8192
    // total ~19.95 MB of d_ws

    // agg + denom must start at zero (ws is poisoned every launch)
    hipMemsetAsync(agg, 0, (size_t)(1048576 + 16384) * sizeof(float), stream);

    k1_linmaps<<<216, 256, 0, stream>>>(x, Wf, bf, Wv, bv, featp, valp, invn);
    k2_compact<<<1, 64, 0, stream>>>(points, cp, counts, slot);
    k3_gather<<<dim3(64, 4), 64, 0, stream>>>(featp, valp, cp, counts, cn, vc);
    k4_sim<<<dim3(54, 4), 256, 0, stream>>>(featp, invn, cn, valp, counts,
                                            alpha, beta, agg, denom);
    k5_out<<<NPTS / 4, 256, 0, stream>>>(agg, vc, denom, slot, Wp, bp, out);
}

// Round 2
// 282.961 us; speedup vs baseline: 1.1826x; 1.1826x over previous
//
#include <hip/hip_runtime.h>
#include <math.h>
#include <float.h>
#include <limits.h>

// Problem constants
#define PIX    13824   // 64*216
#define QPIX   3456    // 32*108
#define QW     108
#define QH     32
#define NPTS   8192
#define MCAP   3072    // per-quadrant center capacity (expected ~2048, 26 sigma)
#define KTILES 54      // QPIX/64
#define SPLITS 8       // center-range splits for k4a

// ---------------------------------------------------------------------------
// K1: feat/value linear maps + fold to [r][k][c] pixel-major + feat inv-norm
// ---------------------------------------------------------------------------
__global__ __launch_bounds__(256) void k1_linmaps(
    const float* __restrict__ x, const float* __restrict__ Wf, const float* __restrict__ bf,
    const float* __restrict__ Wv, const float* __restrict__ bv,
    float* __restrict__ featp, float* __restrict__ valp, float* __restrict__ invn)
{
    __shared__ float ssq[4][64];
    int t = threadIdx.x;
    int lane = t & 63;
    int q = t >> 6;                       // wave id -> o-group (wave-uniform)
    int pix = blockIdx.x * 64 + lane;     // 216*64 = 13824 exact
    int h = pix / 216;
    int w = pix - h * 216;
    int r = ((h >> 5) << 1) | (w >= QW ? 1 : 0);
    int k = (h & 31) * QW + (w >= QW ? w - QW : w);

    float xr[64];
    #pragma unroll
    for (int c = 0; c < 64; c++) xr[c] = x[c * PIX + pix];

    size_t base = ((size_t)(r * QPIX + k)) * 64 + q * 16;
    float ss = 0.0f;
    for (int i = 0; i < 16; i++) {
        int o = q * 16 + i;               // wave-uniform
        float af = bf[o], av = bv[o];
        #pragma unroll
        for (int c = 0; c < 64; c++) {
            af = fmaf(Wf[o * 64 + c], xr[c], af);
            av = fmaf(Wv[o * 64 + c], xr[c], av);
        }
        featp[base + i] = af;
        valp[base + i]  = av;
        ss += af * af;
    }
    ssq[q][lane] = ss;
    __syncthreads();
    if (q == 0) {
        float tot = ssq[0][lane] + ssq[1][lane] + ssq[2][lane] + ssq[3][lane];
        invn[r * QPIX + k] = 1.0f / fmaxf(sqrtf(tot), 1e-12f);
    }
}

// ---------------------------------------------------------------------------
// K2 (hierarchical, order-preserving compaction):
//   k2a: per-64-point-chunk quadrant counts (128 chunks)
//   k2b: per-quadrant exclusive scan of chunk counts (wave shfl scan)
//   k2c: ranked scatter using chunk base + ballot rank
// ---------------------------------------------------------------------------
__device__ __forceinline__ int point_quadrant(float px, float py) {
    // rh = 384/2 = 192 exact, rw = 1296/2 = 648 exact
    return ((py > 192.0f) ? 2 : 0) + ((px > 648.0f) ? 1 : 0);
}

__global__ __launch_bounds__(64) void k2a_count(
    const float* __restrict__ points, int* __restrict__ ccnt)
{
    int lane = threadIdx.x;
    int chunk = blockIdx.x;
    float2 p = ((const float2*)points)[chunk * 64 + lane];
    int q = point_quadrant(p.x, p.y);
    #pragma unroll
    for (int r = 0; r < 4; r++) {
        unsigned long long m = __ballot(q == r);
        if (lane == 0) ccnt[chunk * 4 + r] = __popcll(m);
    }
}

__global__ __launch_bounds__(256) void k2b_scan(
    const int* __restrict__ ccnt, int* __restrict__ cbase, int* __restrict__ counts)
{
    int t = threadIdx.x;
    int r = t >> 6;        // wave = quadrant
    int lane = t & 63;     // lane handles chunks 2*lane, 2*lane+1
    int c0 = ccnt[(2 * lane) * 4 + r];
    int c1 = ccnt[(2 * lane + 1) * 4 + r];
    int pair = c0 + c1;
    int incl = pair;
    #pragma unroll
    for (int d = 1; d < 64; d <<= 1) {
        int n = __shfl_up(incl, d, 64);
        if (lane >= d) incl += n;
    }
    int excl = incl - pair;
    cbase[r * 128 + 2 * lane]     = excl;
    cbase[r * 128 + 2 * lane + 1] = excl + c0;
    if (lane == 63) counts[r] = incl;
}

__global__ __launch_bounds__(64) void k2c_scatter(
    const float* __restrict__ points, const int* __restrict__ cbase,
    float* __restrict__ cp, int* __restrict__ slot)
{
    int lane = threadIdx.x;
    int chunk = blockIdx.x;
    int n = chunk * 64 + lane;
    float2 p = ((const float2*)points)[n];
    int q = point_quadrant(p.x, p.y);
    unsigned long long below = (lane == 0) ? 0ull : (~0ull >> (64 - lane));
    #pragma unroll
    for (int r = 0; r < 4; r++) {
        unsigned long long m = __ballot(q == r);
        if (q == r) {
            int pos = cbase[r * 128 + chunk] + __popcll(m & below);
            ((float2*)cp)[r * MCAP + pos] = p;
            slot[n] = r * MCAP + pos;
        }
    }
}

// ---------------------------------------------------------------------------
// K3: bilinear gather (border clamp) of feat & value at compacted points;
// slot m == K_r is the phantom (0,0) padded row.
// ---------------------------------------------------------------------------
__global__ __launch_bounds__(64) void k3_gather(
    const float* __restrict__ featp, const float* __restrict__ valp,
    const float* __restrict__ cp, const int* __restrict__ counts,
    float* __restrict__ cn, float* __restrict__ vc)
{
    int r = blockIdx.y;
    int m = blockIdx.x * 64 + threadIdx.x;
    int K = counts[r];
    int Mr = min(K + 1, MCAP);
    if (m >= Mr) return;
    float px = 0.0f, py = 0.0f;
    if (m < K) { float2 p = ((const float2*)cp)[r * MCAP + m]; px = p.x; py = p.y; }

    // mirror reference op order: grid = p/(S-1)*2-1 ; g = (grid+1)*(D/2)-0.5
    float gx = (px / 1295.0f * 2.0f - 1.0f + 1.0f) * 54.0f - 0.5f;
    float gy = (py / 383.0f  * 2.0f - 1.0f + 1.0f) * 16.0f - 0.5f;
    float x0 = floorf(gx), y0 = floorf(gy);
    float wx = gx - x0, wy = gy - y0;
    int x0i = (int)fminf(fmaxf(x0,         0.0f), 107.0f);
    int x1i = (int)fminf(fmaxf(x0 + 1.0f,  0.0f), 107.0f);
    int y0i = (int)fminf(fmaxf(y0,         0.0f), 31.0f);
    int y1i = (int)fminf(fmaxf(y0 + 1.0f,  0.0f), 31.0f);
    float w00 = (1.0f - wx) * (1.0f - wy);
    float w01 = wx * (1.0f - wy);
    float w10 = (1.0f - wx) * wy;
    float w11 = wx * wy;

    size_t b00 = ((size_t)(r * QPIX + y0i * QW + x0i)) * 64;
    size_t b01 = ((size_t)(r * QPIX + y0i * QW + x1i)) * 64;
    size_t b10 = ((size_t)(r * QPIX + y1i * QW + x0i)) * 64;
    size_t b11 = ((size_t)(r * QPIX + y1i * QW + x1i)) * 64;
    size_t ob  = ((size_t)(r * MCAP + m)) * 64;

    float fr[64];
    float ss = 0.0f;
    #pragma unroll
    for (int c = 0; c < 64; c += 4) {
        float4 a  = *(const float4*)(featp + b00 + c);
        float4 b_ = *(const float4*)(featp + b01 + c);
        float4 g  = *(const float4*)(featp + b10 + c);
        float4 d  = *(const float4*)(featp + b11 + c);
        float e0 = a.x * w00 + b_.x * w01 + g.x * w10 + d.x * w11;
        float e1 = a.y * w00 + b_.y * w01 + g.y * w10 + d.y * w11;
        float e2 = a.z * w00 + b_.z * w01 + g.z * w10 + d.z * w11;
        float e3 = a.w * w00 + b_.w * w01 + g.w * w10 + d.w * w11;
        fr[c] = e0; fr[c+1] = e1; fr[c+2] = e2; fr[c+3] = e3;
        ss += e0*e0; ss += e1*e1; ss += e2*e2; ss += e3*e3;
    }
    float inv = 1.0f / fmaxf(sqrtf(ss), 1e-12f);
    #pragma unroll
    for (int c = 0; c < 64; c += 4) {
        *(float4*)(cn + ob + c) =
            make_float4(fr[c]*inv, fr[c+1]*inv, fr[c+2]*inv, fr[c+3]*inv);
    }
    #pragma unroll
    for (int c = 0; c < 64; c += 4) {
        float4 a  = *(const float4*)(valp + b00 + c);
        float4 b_ = *(const float4*)(valp + b01 + c);
        float4 g  = *(const float4*)(valp + b10 + c);
        float4 d  = *(const float4*)(valp + b11 + c);
        float4 o;
        o.x = a.x * w00 + b_.x * w01 + g.x * w10 + d.x * w11;
        o.y = a.y * w00 + b_.y * w01 + g.y * w10 + d.y * w11;
        o.z = a.z * w00 + b_.z * w01 + g.z * w10 + d.z * w11;
        o.w = a.w * w00 + b_.w * w01 + g.w * w10 + d.w * w11;
        *(float4*)(vc + ob + c) = o;
    }
}

// ---------------------------------------------------------------------------
// K4a: cosine-sim running argmax over a CENTER SUB-RANGE (split-K style).
// Grid (KTILES, SPLITS, 4). Each block: 64 keys x [t0,t1) center tiles.
// Writes per-(ktile,split) best_s / best_m for each key.
// ---------------------------------------------------------------------------
#define AS 68
__global__ __launch_bounds__(256) void k4a_sim(
    const float* __restrict__ featp, const float* __restrict__ invn,
    const float* __restrict__ cn, const int* __restrict__ counts,
    const float* __restrict__ alpha_p, const float* __restrict__ beta_p,
    float* __restrict__ part_s, int* __restrict__ part_m)
{
    __shared__ float A[64 * AS];
    __shared__ float B[64 * AS];
    __shared__ float rs[16][17];
    __shared__ int   rm[16][17];

    int r     = blockIdx.z;
    int kt    = blockIdx.x;
    int split = blockIdx.y;
    int k0 = kt * 64;
    int t  = threadIdx.x;
    int tx = t & 15, ty = t >> 4;
    int K  = counts[r];
    int Mr = min(K + 1, MCAP);
    float alpha = alpha_p[0], beta = beta_p[0];

    int ntiles = (Mr + 63) >> 6;
    int tps = (ntiles + SPLITS - 1) / SPLITS;
    int ct0 = split * tps;
    int ct1 = min(ntiles, ct0 + tps);

    float best_s[4] = {-INFINITY, -INFINITY, -INFINITY, -INFINITY};
    int   best_m[4] = {INT_MAX, INT_MAX, INT_MAX, INT_MAX};

    if (ct0 < ct1) {
        // load B tile: 64 keys x 64 ch, normalized (xn)
        {
            int j = t >> 2, cq = (t & 3) * 16;
            float inv = invn[r * QPIX + k0 + j];
            const float* src = featp + ((size_t)(r * QPIX + k0 + j)) * 64 + cq;
            float* dst = B + j * AS + cq;
            #pragma unroll
            for (int i = 0; i < 16; i += 4) {
                float4 fv = *(const float4*)(src + i);
                fv.x *= inv; fv.y *= inv; fv.z *= inv; fv.w *= inv;
                *(float4*)(dst + i) = fv;
            }
        }
        for (int ct = ct0; ct < ct1; ct++) {
            __syncthreads();   // previous tile's A reads done (also covers B load)
            {
                int row = t >> 2, cq = (t & 3) * 16;
                int mg = min(ct * 64 + row, MCAP - 1);
                const float* src = cn + ((size_t)(r * MCAP + mg)) * 64 + cq;
                float* dst = A + row * AS + cq;
                #pragma unroll
                for (int i = 0; i < 16; i += 4)
                    *(float4*)(dst + i) = *(const float4*)(src + i);
            }
            __syncthreads();

            float dot[4][4] = {};
            #pragma unroll
            for (int cc = 0; cc < 64; cc += 4) {
                float4 av[4], bv[4];
                #pragma unroll
                for (int u = 0; u < 4; u++) av[u] = *(const float4*)(A + (ty + 16*u) * AS + cc);
                #pragma unroll
                for (int v = 0; v < 4; v++) bv[v] = *(const float4*)(B + (tx + 16*v) * AS + cc);
                #pragma unroll
                for (int u = 0; u < 4; u++) {
                    #pragma unroll
                    for (int v = 0; v < 4; v++) {
                        dot[u][v] = fmaf(av[u].x, bv[v].x, dot[u][v]);
                        dot[u][v] = fmaf(av[u].y, bv[v].y, dot[u][v]);
                        dot[u][v] = fmaf(av[u].z, bv[v].z, dot[u][v]);
                        dot[u][v] = fmaf(av[u].w, bv[v].w, dot[u][v]);
                    }
                }
            }
            // running argmax; m ascending within thread; strict > keeps
            // smallest m on exact fp32 ties (reference first-max rule)
            #pragma unroll
            for (int u = 0; u < 4; u++) {
                int mg = ct * 64 + ty + 16 * u;
                bool valid = mg < Mr;
                #pragma unroll
                for (int v = 0; v < 4; v++) {
                    float s = fmaf(alpha, dot[u][v], beta);  // monotone w/ sigmoid
                    if (valid && s > best_s[v]) { best_s[v] = s; best_m[v] = mg; }
                }
            }
        }
    }

    // cross-thread (ty) reduce per key; tie -> smaller m; store partials
    size_t pb = ((size_t)((r * KTILES + kt) * SPLITS + split)) * 64;
    #pragma unroll
    for (int v = 0; v < 4; v++) {
        __syncthreads();
        rs[ty][tx] = best_s[v]; rm[ty][tx] = best_m[v];
        __syncthreads();
        for (int st = 8; st > 0; st >>= 1) {
            if (ty < st) {
                float s2 = rs[ty + st][tx]; int m2 = rm[ty + st][tx];
                if (s2 > rs[ty][tx] || (s2 == rs[ty][tx] && m2 < rm[ty][tx])) {
                    rs[ty][tx] = s2; rm[ty][tx] = m2;
                }
            }
            __syncthreads();
        }
        if (ty == 0) { part_s[pb + tx + 16 * v] = rs[0][tx]; part_m[pb + tx + 16 * v] = rm[0][tx]; }
    }
}

// ---------------------------------------------------------------------------
// K4b: reduce split partials per key (tie -> smaller m), sigmoid, scatter.
// Grid (KTILES, 4) x 256; 4 threads per key, 16 channels each.
// ---------------------------------------------------------------------------
__global__ __launch_bounds__(256) void k4b_scatter(
    const float* __restrict__ part_s, const int* __restrict__ part_m,
    const float* __restrict__ valp, const int* __restrict__ counts,
    float* __restrict__ agg, float* __restrict__ denom)
{
    int r  = blockIdx.y;
    int kt = blockIdx.x;
    int t  = threadIdx.x;
    int j = t >> 2, cq = (t & 3) * 16;
    int K = counts[r];

    size_t pb = ((size_t)((r * KTILES + kt) * SPLITS)) * 64;
    float bs = -INFINITY; int bm = INT_MAX;
    #pragma unroll
    for (int s = 0; s < SPLITS; s++) {
        float s2 = part_s[pb + (size_t)s * 64 + j];
        int   m2 = part_m[pb + (size_t)s * 64 + j];
        if (s2 > bs || (s2 == bs && m2 < bm)) { bs = s2; bm = m2; }
    }
    if (bm < K) {   // skip phantom / empty winners
        float wgt = 1.0f / (1.0f + expf(-bs));
        float* ad = agg + ((size_t)(r * MCAP + bm)) * 64 + cq;
        const float* vsrc = valp + ((size_t)(r * QPIX + kt * 64 + j)) * 64 + cq;
        #pragma unroll
        for (int i = 0; i < 16; i++) atomicAdd(ad + i, wgt * vsrc[i]);
        if ((t & 3) == 0) atomicAdd(denom + r * MCAP + bm, wgt);
    }
}

// ---------------------------------------------------------------------------
// K5: per-point output + projection + transposed store [1,64,1,8192]
// ---------------------------------------------------------------------------
__global__ __launch_bounds__(256) void k5_out(
    const float* __restrict__ agg, const float* __restrict__ vc,
    const float* __restrict__ denom, const int* __restrict__ slot,
    const float* __restrict__ Wp, const float* __restrict__ bp,
    float* __restrict__ out)
{
    __shared__ float WT[64 * 65];
    __shared__ float ov[4][64];
    __shared__ float res[4][64];
    int t = threadIdx.x;
    {
        int o = t >> 2, cq = (t & 3) * 16;
        #pragma unroll
        for (int i = 0; i < 16; i += 4) {
            float4 wv = *(const float4*)(Wp + o * 64 + cq + i);
            WT[(cq + i + 0) * 65 + o] = wv.x;
            WT[(cq + i + 1) * 65 + o] = wv.y;
            WT[(cq + i + 2) * 65 + o] = wv.z;
            WT[(cq + i + 3) * 65 + o] = wv.w;
        }
    }
    int p = t >> 6, c = t & 63;
    int n = blockIdx.x * 4 + p;
    int sl = slot[n];
    float d = denom[sl] + 1.0f;
    float o_v = (agg[(size_t)sl * 64 + c] + vc[(size_t)sl * 64 + c]) / d;
    ov[p][c] = o_v;
    unsigned long long nz = __ballot(o_v != 0.0f);   // wave == point
    __syncthreads();
    float acc = bp[c];
    #pragma unroll
    for (int cc = 0; cc < 64; cc++)
        acc = fmaf(ov[p][cc], WT[cc * 65 + c], acc);
    res[p][c] = (nz != 0ull) ? acc : 0.0f;
    __syncthreads();
    if (t < 64) {
        float4 val = make_float4(res[0][t], res[1][t], res[2][t], res[3][t]);
        *(float4*)(out + (size_t)t * NPTS + blockIdx.x * 4) = val;
    }
}

// ---------------------------------------------------------------------------
extern "C" void kernel_launch(void* const* d_in, const int* in_sizes, int n_in,
                              void* d_out, int out_size, void* d_ws, size_t ws_size,
                              hipStream_t stream) {
    const float* points = (const float*)d_in[0];
    const float* x      = (const float*)d_in[1];
    const float* Wf     = (const float*)d_in[2];
    const float* bf     = (const float*)d_in[3];
    const float* Wv     = (const float*)d_in[4];
    const float* bv     = (const float*)d_in[5];
    const float* Wp     = (const float*)d_in[6];
    const float* bp     = (const float*)d_in[7];
    const float* alpha  = (const float*)d_in[8];
    const float* beta   = (const float*)d_in[9];
    float* out = (float*)d_out;

    float* ws    = (float*)d_ws;
    float* featp = ws;                        // 884736
    float* valp  = featp + 884736;            // 884736
    float* cn    = valp  + 884736;            // 786432 (4*MCAP*64)
    float* vc    = cn    + 786432;            // 786432
    float* agg   = vc    + 786432;            // 786432
    float* denom = agg   + 786432;            // 12288 (4*MCAP)
    float* invn  = denom + 12288;             // 13824
    float* cp    = invn  + 13824;             // 24576 (2*4*MCAP)
    float* part_s= cp    + 24576;             // 110592 (4*54*8*64)
    int*   part_m= (int*)(part_s + 110592);   // 110592
    int*   ccnt  = part_m + 110592;           // 512
    int*   cbase = ccnt   + 512;              // 512
    int*   counts= cbase  + 512;              // 16
    int*   slot  = counts + 16;               // 8192
    // total ~17.7 MB of d_ws

    // agg + denom must start at zero (ws is poisoned every launch)
    hipMemsetAsync(agg, 0, (size_t)(786432 + 12288) * sizeof(float), stream);

    k1_linmaps<<<216, 256, 0, stream>>>(x, Wf, bf, Wv, bv, featp, valp, invn);
    k2a_count  <<<128, 64, 0, stream>>>(points, ccnt);
    k2b_scan   <<<1, 256, 0, stream>>>(ccnt, cbase, counts);
    k2c_scatter<<<128, 64, 0, stream>>>(points, cbase, cp, slot);
    k3_gather<<<dim3(MCAP / 64, 4), 64, 0, stream>>>(featp, valp, cp, counts, cn, vc);
    k4a_sim<<<dim3(KTILES, SPLITS, 4), 256, 0, stream>>>(featp, invn, cn, counts,
                                                         alpha, beta, part_s, part_m);
    k4b_scatter<<<dim3(KTILES, 4), 256, 0, stream>>>(part_s, part_m, valp, counts,
                                                     agg, denom);
    k5_out<<<NPTS / 4, 256, 0, stream>>>(agg, vc, denom, slot, Wp, bp, out);
}